// Round 6
// baseline (94.150 us; speedup 1.0000x reference)
//
#include <hip/hip_runtime.h>
#include <hip/hip_bf16.h>

// out[b] = adj @ (x[b] @ W) + bias ; B=64, N=4096, F_IN=F_OUT=32
// R21: STAGING-BYTES TEST — 256Mx128N tile, 1 blk/CU, SAME per-wave loop.
//   R20 post-mortem: prep 32.9->28.6us (store fix confirmed); GEMM pinned at
//   61.5us. Accounting: staging 1.07GB/61.5us = 17.5 TB/s = 28 B/cyc/CU and
//   64KB/CU-step at that rate = 2287cyc = EXACTLY the wall -> H1: gload_lds
//   L2 service is the binding resource; only fewer staged bytes helps
//   (explains R16/R18 nulls: same bytes). Test: 256x128 tile = 0.023 B/MAC
//   (-27%), grid 256 (2 blk/CU impossible above 128^2 at this M,N).
//   Per-wave body IDENTICAL to proven R15 loop: wave 64x128, split-K 2ks,
//   12 frag reads, 32 MFMA, ONE barrier/tile (unlike failed R16/R18:
//   no lgkm-before-barrier, no phase splitting). 8 waves = 4wr x 2ks,
//   dbuf 2x48KB, merge in 128KB dead LDS. XCD region 1024x1024 kept.
//   H1 -> GEMM ~45-50us; if ~R16's 70 -> structural ceiling, revert.
// Prep = R20 (LDS-transpose support, fused cvt). ws>=50.4MB proven.

#define B_SZ 64
#define N_SZ 4096
#define NT 64

typedef __attribute__((ext_vector_type(8))) short bf16x8;
typedef __attribute__((ext_vector_type(4))) float f32x4;
typedef __attribute__((ext_vector_type(8))) unsigned short u16x8;

__device__ __forceinline__ unsigned short f2bf(float f) {
  unsigned int u = __float_as_uint(f);
  u += 0x7fffu + ((u >> 16) & 1u);
  return (unsigned short)(u >> 16);
}

// ---- support: x @ W -> bf16 St[o-major 2048][4096], 16B-coalesced stores ---
__device__ __forceinline__ void support_body_lds(const float* __restrict__ x,
                                                 const float* __restrict__ W,
                                                 unsigned short* __restrict__ St,
                                                 int sbid, int t,
                                                 unsigned short* __restrict__ L) {
  const int b = sbid >> 4;            // 16 blocks per batch row
  const int m0 = (sbid & 15) << 8;    // 256-node range
  const int gid = (sbid << 8) + t;    // = b*4096 + m0 + t
  const float4* xr = (const float4*)(x + (size_t)gid * 32);
  float xv[32];
#pragma unroll
  for (int i = 0; i < 8; ++i) {
    float4 v = xr[i];
    xv[4 * i + 0] = v.x; xv[4 * i + 1] = v.y;
    xv[4 * i + 2] = v.z; xv[4 * i + 3] = v.w;
  }
  // acc over o, park bf16 in padded LDS [256][33]
#pragma unroll
  for (int o = 0; o < 32; ++o) {
    float acc = 0.f;
#pragma unroll
    for (int f = 0; f < 32; ++f) acc = fmaf(xv[f], W[f * 32 + o], acc);
    L[t * 33 + o] = f2bf(acc);
  }
  __syncthreads();
  // cooperative stores: iter it, thread t -> o = it*8 + (t>>5), m-seg (t&31)*8
  const int l32 = t & 31;
#pragma unroll
  for (int it = 0; it < 4; ++it) {
    const int o = it * 8 + (t >> 5);
    u16x8 w;
#pragma unroll
    for (int i = 0; i < 8; ++i) w[i] = L[(l32 * 8 + i) * 33 + o];
    *(u16x8*)(St + ((size_t)(b * 32 + o) << 12) + m0 + l32 * 8) = w;
  }
}

__device__ __forceinline__ void cvt_body(const float* __restrict__ a,
                                         unsigned short* __restrict__ o,
                                         size_t idx8) {
  const size_t i = idx8 * 8;
  const float4* p = (const float4*)(a + i);
  float4 v0 = p[0], v1 = p[1];
  u16x8 r;
  r[0] = f2bf(v0.x); r[1] = f2bf(v0.y); r[2] = f2bf(v0.z); r[3] = f2bf(v0.w);
  r[4] = f2bf(v1.x); r[5] = f2bf(v1.y); r[6] = f2bf(v1.z); r[7] = f2bf(v1.w);
  *(u16x8*)(o + i) = r;
}

// ---------------- prep: fused full-adj cvt + support (full path) ------------
__global__ __launch_bounds__(256) void k_prep(const float* __restrict__ x,
                                              const float* __restrict__ adj,
                                              const float* __restrict__ W,
                                              unsigned short* __restrict__ St,
                                              unsigned short* __restrict__ adjB) {
  __shared__ unsigned short L[256 * 33];
  const int bid = blockIdx.x;
  const int t = threadIdx.x;
  if (bid < 8192) cvt_body(adj, adjB, (size_t)bid * 256 + t);
  else support_body_lds(x, W, St, bid - 8192, t, L);
}

// fallback-path kernels
__global__ __launch_bounds__(256) void k_support(const float* __restrict__ x,
                                                 const float* __restrict__ W,
                                                 unsigned short* __restrict__ St) {
  __shared__ unsigned short L[256 * 33];
  support_body_lds(x, W, St, blockIdx.x, threadIdx.x, L);
}
__global__ __launch_bounds__(256) void k_cvt(const float* __restrict__ a,
                                             unsigned short* __restrict__ o) {
  cvt_body(a, o, (size_t)blockIdx.x * 256 + threadIdx.x);
}

// -- GEMM: 256x128, 8 waves (4M x 2KS, wave 64x128), dbuf 2x48KB, 1 blk/CU ---
#define GLOAD16(gp, lp)                                                        \
  __builtin_amdgcn_global_load_lds(                                            \
      (const __attribute__((address_space(1))) void*)(gp),                     \
      (__attribute__((address_space(3))) void*)(lp), 16, 0, 0)
#define PRIO1() __builtin_amdgcn_s_setprio(1)
#define PRIO0() __builtin_amdgcn_s_setprio(0)

__global__ __launch_bounds__(512, 2) void k_gemm9(const unsigned short* __restrict__ Ab,
                                                  const unsigned short* __restrict__ Bm,
                                                  const float* __restrict__ bias,
                                                  float* __restrict__ out,
                                                  int full, int rowoff) {
  __shared__ __attribute__((aligned(16))) char SM[131072];
  char* Lc = SM;            // current tile buf: [A 32KB][B 16KB]
  char* Lo = SM + 49152;    // other buf
  const int t = threadIdx.x;
  const int wg = blockIdx.x;
  int bm0, bn0;
  if (full) {
    // XCD region 1024x1024 (rm = xcd>>1, rn = xcd&1): 4 m-tiles x 8 n-tiles
    const int xcd = wg & 7;
    const int idx = wg >> 3;   // 0..31
    bm0 = ((xcd >> 1) << 10) + ((idx >> 3) << 8);
    bn0 = ((xcd & 1) << 10) + ((idx & 7) << 7);
  } else {
    // fallback half-split path (Ab is a 2048-row panel); grid 128
    bm0 = (wg >> 4) << 8;
    bn0 = (wg & 15) << 7;
  }
  const int lane = t & 63;
  const int wid = t >> 6;          // 0..7
  const int wr = wid & 3;          // M-quarter (64 rows)
  const int ks = wid >> 2;         // split-K team: kk-half of BK=64

  f32x4 acc[4][8];
#pragma unroll
  for (int i = 0; i < 4; ++i)
#pragma unroll
    for (int j = 0; j < 8; ++j) acc[i][j] = (f32x4){0.f, 0.f, 0.f, 0.f};

  // staging: 6 gloads/tile (A 4 + B 2), each 512thr x 16B = 8KB = 64 rows
  const int srow = t >> 3;   // 0..63
  const int as = t & 7;
  const int swz = (as ^ (srow & 7)) << 4;  // inverse-swizzled source (rule #21)
  const size_t a_s0 = ((size_t)(bm0 + srow) << 13) + (size_t)swz;
  const size_t b_s0 = ((size_t)(bn0 + srow) << 13) + (size_t)swz;
  const int t16 = t * 16;
  const char* A8 = (const char*)Ab;
  const char* B8 = (const char*)Bm;

#define STAGE(KT_, Ld)                                                         \
  do {                                                                         \
    const size_t kb = (size_t)(KT_) << 7;                                      \
    GLOAD16(A8 + a_s0 + kb,           (Ld) + t16);                             \
    GLOAD16(A8 + a_s0 + 524288 + kb,  (Ld) + 8192 + t16);                      \
    GLOAD16(A8 + a_s0 + 1048576 + kb, (Ld) + 16384 + t16);                     \
    GLOAD16(A8 + a_s0 + 1572864 + kb, (Ld) + 24576 + t16);                     \
    GLOAD16(B8 + b_s0 + kb,           (Ld) + 32768 + t16);                     \
    GLOAD16(B8 + b_s0 + 524288 + kb,  (Ld) + 40960 + t16);                     \
  } while (0)

  // fragment LDS byte offsets (kk = ks per team; XOR swizzle, proven)
  const int cbase = (ks * 64 + ((lane >> 4) << 4)) ^ ((lane & 7) << 4);
  int aoff[4], boff[8];
#pragma unroll
  for (int mi = 0; mi < 4; ++mi)
    aoff[mi] = (wr * 64 + mi * 16 + (lane & 15)) * 128 + cbase;
#pragma unroll
  for (int ni = 0; ni < 8; ++ni)
    boff[ni] = 32768 + (ni * 16 + (lane & 15)) * 128 + cbase;

  // prologue: tile 0 into buf0
  STAGE(0, Lc);
  __syncthreads();  // drains the 6 DMA loads

  for (int kt = 0; kt < NT; ++kt) {
    // 1) issue next tile's DMA first (max latency cover before the sync)
    if (kt + 1 < NT) STAGE(kt + 1, Lo);
    // 2) team frag reads (A 4 + B 8 = 12 ds_read_b128)
    bf16x8 a[4], b[8];
#pragma unroll
    for (int mi = 0; mi < 4; ++mi) a[mi] = *(const bf16x8*)(Lc + aoff[mi]);
#pragma unroll
    for (int ni = 0; ni < 8; ++ni) b[ni] = *(const bf16x8*)(Lc + boff[ni]);
    // 3) 32 MFMA (team's kk-half, 64x128 wave tile)
    PRIO1();
#pragma unroll
    for (int mi = 0; mi < 4; ++mi)
#pragma unroll
      for (int ni = 0; ni < 8; ++ni)
        acc[mi][ni] = __builtin_amdgcn_mfma_f32_16x16x32_bf16(
            a[mi], b[ni], acc[mi][ni], 0, 0, 0);
    PRIO0();
    // 4) barrier (drains DMA; covered by the other 7 waves' stagger)
    __syncthreads();
    { char* tp_ = Lc; Lc = Lo; Lo = tp_; }
  }

  // ------- split-K merge through LDS (dbuf dead; 4 x 32KB wr-regions) -------
  if (ks == 1) {
    char* mb = SM + (wr << 15);
#pragma unroll
    for (int mi = 0; mi < 4; ++mi)
#pragma unroll
      for (int ni = 0; ni < 8; ++ni)
        *(f32x4*)(mb + (((mi * 8 + ni) << 6) + lane) * 16) = acc[mi][ni];
  }
  __syncthreads();
  if (ks == 0) {
    char* mb = SM + (wr << 15);
#pragma unroll
    for (int mi = 0; mi < 4; ++mi)
#pragma unroll
      for (int ni = 0; ni < 8; ++ni)
        acc[mi][ni] += *(const f32x4*)(mb + (((mi * 8 + ni) << 6) + lane) * 16);
    // ---- epilogue: C/D layout col=lane&15, row=(lane>>4)*4+q (proven) ----
    const float blo = bias[lane & 15];
    const float bhi = bias[(lane & 15) + 16];
#pragma unroll
    for (int mi = 0; mi < 4; ++mi) {
#pragma unroll
      for (int ni = 0; ni < 8; ++ni) {
        const float badd = (ni & 1) ? bhi : blo;
#pragma unroll
        for (int q = 0; q < 4; ++q) {
          const int n = rowoff + bm0 + wr * 64 + mi * 16 + ((lane >> 4) << 2) + q;
          const int cidx = bn0 + ni * 16 + (lane & 15);
          const int bb = cidx >> 5;
          const int o = cidx & 31;
          out[(((size_t)bb << 12) + n) * 32 + o] = acc[mi][ni][q] + badd;
        }
      }
    }
  }
}

extern "C" void kernel_launch(void* const* d_in, const int* in_sizes, int n_in,
                              void* d_out, int out_size, void* d_ws, size_t ws_size,
                              hipStream_t stream) {
  const float* x = (const float*)d_in[0];
  const float* adj = (const float*)d_in[1];
  const float* W = (const float*)d_in[2];
  const float* bias = (const float*)d_in[3];
  float* out = (float*)d_out;

  const size_t ST_B = (size_t)2048 * 4096 * 2;      // 16,777,216
  const size_t ADJ_FULL = (size_t)4096 * 4096 * 2;  // 33,554,432

  unsigned short* St = (unsigned short*)d_ws;

  if (ws_size >= ST_B + ADJ_FULL) {
    // full path (proven to run): fused prep + one GEMM (grid 256 = 1 blk/CU)
    unsigned short* adjB = St + (ST_B / 2);
    hipLaunchKernelGGL(k_prep, dim3(9216), dim3(256), 0, stream, x, adj, W, St,
                       adjB);
    hipLaunchKernelGGL(k_gemm9, dim3(256), dim3(512), 0, stream, adjB, St, bias,
                       out, 1, 0);
  } else {
    // fallback half-split (not expected to run): one 2048-row panel reused
    unsigned short* adjH = St + (ST_B / 2);
    hipLaunchKernelGGL(k_support, dim3((B_SZ * N_SZ) / 256), dim3(256), 0,
                       stream, x, W, St);
    hipLaunchKernelGGL(k_cvt, dim3((2048 * 4096) / 2048), dim3(256), 0, stream,
                       adj, adjH);
    hipLaunchKernelGGL(k_gemm9, dim3(128), dim3(512), 0, stream, adjH, St, bias,
                       out, 0, 0);
    hipLaunchKernelGGL(k_cvt, dim3((2048 * 4096) / 2048), dim3(256), 0, stream,
                       adj + (size_t)2048 * 4096, adjH);
    hipLaunchKernelGGL(k_gemm9, dim3(128), dim3(512), 0, stream, adjH, St, bias,
                       out, 0, 2048);
  }
}

// Round 8
// 84.735 us; speedup vs baseline: 1.1111x; 1.1111x over previous
//
#include <hip/hip_runtime.h>
#include <hip/hip_bf16.h>

// out[b] = adj @ (x[b] @ W) + bias ; B=64, N=4096, F_IN=F_OUT=32
// R23: R22 BUGFIX — support loader covered only 1/4 of the tile (thread t
//   loaded flat [8t,8t+8) = 2048 of 8192 floats; LDS rows 64-255 were
//   uninitialized -> NaN). Fix: j=0..3 flat chunks idx8 = t + 256*j
//   (node = idx8>>2, ch = idx8&3) — all 256 nodes, coalesced. All other
//   logic byte-identical to R22.
//   GEMM frozen at its measured roofline (61.5us = ~28 B/cyc/CU gload_lds
//   service cap at 128^2/2blk; 6-variant evidence). Prep: MFMA hi/lo support
//   (3 MFMAs, dropped lo*Wl ~ 2^-16 < St bf16 rounding) kills the serial
//   1024-fma + 1024-W-load VALU tail; R20 transpose store kept.
// ws>=50.4MB proven (R10); half-split fallback kept.

#define B_SZ 64
#define N_SZ 4096
#define NT 64

typedef __attribute__((ext_vector_type(8))) short bf16x8;
typedef __attribute__((ext_vector_type(4))) float f32x4;
typedef __attribute__((ext_vector_type(8))) unsigned short u16x8;

__device__ __forceinline__ unsigned short f2bf(float f) {
  unsigned int u = __float_as_uint(f);
  u += 0x7fffu + ((u >> 16) & 1u);
  return (unsigned short)(u >> 16);
}
__device__ __forceinline__ float bf2f(unsigned short h) {
  return __uint_as_float(((unsigned int)h) << 16);
}

// ---- support: St[(b,o)][m] = (x@W) in bf16 via hi/lo-split MFMA ------------
// SB layout: Ah[0,16K) Al[16K,32K) Wh[32K,34K) Wl[34K,36K); transpose L
// reuses [0,16.9K) after the MFMA phase.
__device__ __forceinline__ void support_mfma(const float* __restrict__ x,
                                             const float* __restrict__ W,
                                             unsigned short* __restrict__ St,
                                             int sbid, int t, char* SB) {
  unsigned short* Ah = (unsigned short*)SB;
  unsigned short* Al = (unsigned short*)(SB + 16384);
  unsigned short* Wh = (unsigned short*)(SB + 32768);
  unsigned short* Wl = (unsigned short*)(SB + 34816);
  const int b = sbid >> 4;           // 16 blocks per batch
  const int m0 = (sbid & 15) << 8;   // 256-node range
  // x tile: 256 nodes x 32 f = 8192 f32. j=0..3: flat 8-float chunk
  // idx8 = t + 256*j -> node = idx8>>2, ch = idx8&3. Coalesced.
  const float* xb = x + ((size_t)sbid << 13);
#pragma unroll
  for (int j = 0; j < 4; ++j) {
    const int idx8 = t + 256 * j;
    const int node = idx8 >> 2;
    const int ch = idx8 & 3;
    const float4* xp = (const float4*)(xb + (size_t)idx8 * 8);
    float4 v0 = xp[0], v1 = xp[1];
    float vv[8] = {v0.x, v0.y, v0.z, v0.w, v1.x, v1.y, v1.z, v1.w};
    u16x8 hi, lo;
#pragma unroll
    for (int i = 0; i < 8; ++i) {
      unsigned short h = f2bf(vv[i]);
      hi[i] = h;
      lo[i] = f2bf(vv[i] - bf2f(h));
    }
    const int aoffb = node * 64 + ((ch ^ (node & 3)) << 4);
    *(u16x8*)((char*)Ah + aoffb) = hi;
    *(u16x8*)((char*)Al + aoffb) = lo;
  }
  // W^T hi/lo: elems e = 4t..4t+3 ; o = e>>5, f = e&31 (4KB, L2-hot)
#pragma unroll
  for (int i = 0; i < 4; ++i) {
    const int e = t * 4 + i;
    const int o = e >> 5;
    const int f = e & 31;
    const float wv = W[f * 32 + o];
    const unsigned short wh = f2bf(wv);
    const unsigned short wl = f2bf(wv - bf2f(wh));
    const int wb = o * 64 + ((((f >> 3) ^ (o & 3)) << 4)) + (f & 7) * 2;
    *(unsigned short*)((char*)Wh + wb) = wh;
    *(unsigned short*)((char*)Wl + wb) = wl;
  }
  __syncthreads();
  const int lane = t & 63;
  const int wid = t >> 6;   // wave handles nodes [64*wid, 64*wid+64)
  const int kch = lane >> 4;
  bf16x8 ah[4], al[4], bh[2], bl[2];
#pragma unroll
  for (int mi = 0; mi < 4; ++mi) {
    const int row = wid * 64 + mi * 16 + (lane & 15);
    const int off = row * 64 + ((kch ^ (row & 3)) << 4);
    ah[mi] = *(const bf16x8*)((char*)Ah + off);
    al[mi] = *(const bf16x8*)((char*)Al + off);
  }
#pragma unroll
  for (int nj = 0; nj < 2; ++nj) {
    const int o = nj * 16 + (lane & 15);
    const int off = o * 64 + ((kch ^ (o & 3)) << 4);
    bh[nj] = *(const bf16x8*)((char*)Wh + off);
    bl[nj] = *(const bf16x8*)((char*)Wl + off);
  }
  f32x4 acc[4][2];
#pragma unroll
  for (int mi = 0; mi < 4; ++mi)
#pragma unroll
    for (int nj = 0; nj < 2; ++nj) {
      acc[mi][nj] = (f32x4){0.f, 0.f, 0.f, 0.f};
      acc[mi][nj] = __builtin_amdgcn_mfma_f32_16x16x32_bf16(ah[mi], bl[nj],
                                                            acc[mi][nj], 0, 0, 0);
      acc[mi][nj] = __builtin_amdgcn_mfma_f32_16x16x32_bf16(al[mi], bh[nj],
                                                            acc[mi][nj], 0, 0, 0);
      acc[mi][nj] = __builtin_amdgcn_mfma_f32_16x16x32_bf16(ah[mi], bh[nj],
                                                            acc[mi][nj], 0, 0, 0);
    }
  __syncthreads();  // Ah/Al dead; reuse as transpose buffer
  unsigned short* L = (unsigned short*)SB;  // [256][33]
#pragma unroll
  for (int mi = 0; mi < 4; ++mi)
#pragma unroll
    for (int nj = 0; nj < 2; ++nj)
#pragma unroll
      for (int q = 0; q < 4; ++q) {
        const int nl = wid * 64 + mi * 16 + ((lane >> 4) << 2) + q;
        const int o = nj * 16 + (lane & 15);
        L[nl * 33 + o] = f2bf(acc[mi][nj][q]);
      }
  __syncthreads();
  // R20-proven coalesced store: wave instr covers contiguous 512B segments
  const int l32 = t & 31;
#pragma unroll
  for (int it = 0; it < 4; ++it) {
    const int o = it * 8 + (t >> 5);
    u16x8 w;
#pragma unroll
    for (int i = 0; i < 8; ++i) w[i] = L[(l32 * 8 + i) * 33 + o];
    *(u16x8*)(St + ((size_t)(b * 32 + o) << 12) + m0 + l32 * 8) = w;
  }
}

__device__ __forceinline__ void cvt_body(const float* __restrict__ a,
                                         unsigned short* __restrict__ o,
                                         size_t idx8) {
  const size_t i = idx8 * 8;
  const float4* p = (const float4*)(a + i);
  float4 v0 = p[0], v1 = p[1];
  u16x8 r;
  r[0] = f2bf(v0.x); r[1] = f2bf(v0.y); r[2] = f2bf(v0.z); r[3] = f2bf(v0.w);
  r[4] = f2bf(v1.x); r[5] = f2bf(v1.y); r[6] = f2bf(v1.z); r[7] = f2bf(v1.w);
  *(u16x8*)(o + i) = r;
}

// ---------------- prep: fused support (first) + full-adj cvt ----------------
__global__ __launch_bounds__(256) void k_prep(const float* __restrict__ x,
                                              const float* __restrict__ adj,
                                              const float* __restrict__ W,
                                              unsigned short* __restrict__ St,
                                              unsigned short* __restrict__ adjB) {
  __shared__ __attribute__((aligned(16))) char SB[36864];
  const int bid = blockIdx.x;
  const int t = threadIdx.x;
  if (bid < 1024) support_mfma(x, W, St, bid, t, SB);
  else cvt_body(adj, adjB, (size_t)(bid - 1024) * 256 + t);
}

// fallback-path kernels
__global__ __launch_bounds__(256) void k_support(const float* __restrict__ x,
                                                 const float* __restrict__ W,
                                                 unsigned short* __restrict__ St) {
  __shared__ __attribute__((aligned(16))) char SB[36864];
  support_mfma(x, W, St, blockIdx.x, threadIdx.x, SB);
}
__global__ __launch_bounds__(256) void k_cvt(const float* __restrict__ a,
                                             unsigned short* __restrict__ o) {
  cvt_body(a, o, (size_t)blockIdx.x * 256 + threadIdx.x);
}

// -- GEMM: 128x128, 4 waves (2M x 2KS, wave 64x128), dbuf 64KB, 2 blk/CU -----
#define GLOAD16(gp, lp)                                                        \
  __builtin_amdgcn_global_load_lds(                                            \
      (const __attribute__((address_space(1))) void*)(gp),                     \
      (__attribute__((address_space(3))) void*)(lp), 16, 0, 0)
#define PRIO1() __builtin_amdgcn_s_setprio(1)
#define PRIO0() __builtin_amdgcn_s_setprio(0)

__global__ __launch_bounds__(256, 2) void k_gemm6(const unsigned short* __restrict__ Ab,
                                                  const unsigned short* __restrict__ Bm,
                                                  const float* __restrict__ bias,
                                                  float* __restrict__ out,
                                                  int nbm, int rowoff) {
  __shared__ __attribute__((aligned(16))) char SM[65536];
  char* Lc = SM;            // current tile buf: [A 16KB][B 16KB]
  char* Lo = SM + 32768;    // other buf
  const int t = threadIdx.x;
  const int wg = blockIdx.x;
  const int xcd = wg & 7;
  const int idx = wg >> 3;
  int bm0, bn0;
  if (nbm == 4) {
    // full path: XCD region = 1024x1024 (rm = xcd>>1, rn = xcd&1), 8x8 tiles.
    bm0 = ((xcd >> 1) << 10) + ((idx >> 3) << 7);
    bn0 = ((xcd & 1) << 10) + ((idx & 7) << 7);
  } else {
    // fallback half-split path
    bm0 = (xcd * nbm + (idx >> 4)) << 7;
    bn0 = (idx & 15) << 7;
  }
  const int lane = t & 63;
  const int wid = t >> 6;          // 0..3
  const int wr = wid & 1;          // M-half (64 rows)
  const int ks = wid >> 1;         // split-K team: kk-half of BK=64

  f32x4 acc[4][8];
#pragma unroll
  for (int i = 0; i < 4; ++i)
#pragma unroll
    for (int j = 0; j < 8; ++j) acc[i][j] = (f32x4){0.f, 0.f, 0.f, 0.f};

  // staging: 8 gloads/tile (A 4 + B 4), each 256thr x 16B = 4KB = 32 rows
  const int srow = t >> 3;   // 0..31
  const int as = t & 7;
  const int swz = (as ^ (srow & 7)) << 4;  // inverse-swizzled source (rule #21)
  const size_t a_s0 = ((size_t)(bm0 + srow) << 13) + (size_t)swz;
  const size_t b_s0 = ((size_t)(bn0 + srow) << 13) + (size_t)swz;
  const int t16 = t * 16;
  const char* A8 = (const char*)Ab;
  const char* B8 = (const char*)Bm;

#define STAGE(KT_, Ld)                                                         \
  do {                                                                         \
    const size_t kb = (size_t)(KT_) << 7;                                      \
    GLOAD16(A8 + a_s0 + kb,          (Ld) + t16);                              \
    GLOAD16(A8 + a_s0 + 262144 + kb, (Ld) + 4096 + t16);                       \
    GLOAD16(A8 + a_s0 + 524288 + kb, (Ld) + 8192 + t16);                       \
    GLOAD16(A8 + a_s0 + 786432 + kb, (Ld) + 12288 + t16);                      \
    GLOAD16(B8 + b_s0 + kb,          (Ld) + 16384 + t16);                      \
    GLOAD16(B8 + b_s0 + 262144 + kb, (Ld) + 20480 + t16);                      \
    GLOAD16(B8 + b_s0 + 524288 + kb, (Ld) + 24576 + t16);                      \
    GLOAD16(B8 + b_s0 + 786432 + kb, (Ld) + 28672 + t16);                      \
  } while (0)

  // fragment LDS byte offsets (kk = ks per team; XOR swizzle, R10-proven)
  const int cbase = (ks * 64 + ((lane >> 4) << 4)) ^ ((lane & 7) << 4);
  int aoff[4], boff[8];
#pragma unroll
  for (int mi = 0; mi < 4; ++mi)
    aoff[mi] = (wr * 64 + mi * 16 + (lane & 15)) * 128 + cbase;
#pragma unroll
  for (int ni = 0; ni < 8; ++ni)
    boff[ni] = 16384 + (ni * 16 + (lane & 15)) * 128 + cbase;

  // prologue: tile 0 into buf0
  STAGE(0, Lc);
  __syncthreads();  // drains the 8 DMA loads

  for (int kt = 0; kt < NT; ++kt) {
    // 1) issue next tile's DMA first (max latency cover before the sync)
    if (kt + 1 < NT) STAGE(kt + 1, Lo);
    // 2) team frag reads (A 4 + B 8 = 12 ds_read_b128)
    bf16x8 a[4], b[8];
#pragma unroll
    for (int mi = 0; mi < 4; ++mi) a[mi] = *(const bf16x8*)(Lc + aoff[mi]);
#pragma unroll
    for (int ni = 0; ni < 8; ++ni) b[ni] = *(const bf16x8*)(Lc + boff[ni]);
    // 3) 32 MFMA (team's kk-half, 64x128 wave tile)
    PRIO1();
#pragma unroll
    for (int mi = 0; mi < 4; ++mi)
#pragma unroll
      for (int ni = 0; ni < 8; ++ni)
        acc[mi][ni] = __builtin_amdgcn_mfma_f32_16x16x32_bf16(
            a[mi], b[ni], acc[mi][ni], 0, 0, 0);
    PRIO0();
    // 4) barrier (drains DMA; covered by sibling block / other waves)
    __syncthreads();
    { char* tp_ = Lc; Lc = Lo; Lo = tp_; }
  }

  // ------- split-K merge through LDS (dbuf is dead now; 32KB per ks1-wave) --
  if (ks == 1) {
    char* mb = SM + (wr << 15);
#pragma unroll
    for (int mi = 0; mi < 4; ++mi)
#pragma unroll
      for (int ni = 0; ni < 8; ++ni)
        *(f32x4*)(mb + (((mi * 8 + ni) << 6) + lane) * 16) = acc[mi][ni];
  }
  __syncthreads();
  if (ks == 0) {
    char* mb = SM + (wr << 15);
#pragma unroll
    for (int mi = 0; mi < 4; ++mi)
#pragma unroll
      for (int ni = 0; ni < 8; ++ni)
        acc[mi][ni] += *(const f32x4*)(mb + (((mi * 8 + ni) << 6) + lane) * 16);
    // ---- epilogue: C/D layout col=lane&15, row=(lane>>4)*4+q (proven) ----
    const float blo = bias[lane & 15];
    const float bhi = bias[(lane & 15) + 16];
#pragma unroll
    for (int mi = 0; mi < 4; ++mi) {
#pragma unroll
      for (int ni = 0; ni < 8; ++ni) {
        const float badd = (ni & 1) ? bhi : blo;
#pragma unroll
        for (int q = 0; q < 4; ++q) {
          const int n = rowoff + bm0 + wr * 64 + mi * 16 + ((lane >> 4) << 2) + q;
          const int cidx = bn0 + ni * 16 + (lane & 15);
          const int bb = cidx >> 5;
          const int o = cidx & 31;
          out[(((size_t)bb << 12) + n) * 32 + o] = acc[mi][ni][q] + badd;
        }
      }
    }
  }
}

extern "C" void kernel_launch(void* const* d_in, const int* in_sizes, int n_in,
                              void* d_out, int out_size, void* d_ws, size_t ws_size,
                              hipStream_t stream) {
  const float* x = (const float*)d_in[0];
  const float* adj = (const float*)d_in[1];
  const float* W = (const float*)d_in[2];
  const float* bias = (const float*)d_in[3];
  float* out = (float*)d_out;

  const size_t ST_B = (size_t)2048 * 4096 * 2;      // 16,777,216
  const size_t ADJ_FULL = (size_t)4096 * 4096 * 2;  // 33,554,432

  unsigned short* St = (unsigned short*)d_ws;

  if (ws_size >= ST_B + ADJ_FULL) {
    // full path (proven to run): fused prep + one GEMM (grid 512 = 2 blk/CU)
    unsigned short* adjB = St + (ST_B / 2);
    hipLaunchKernelGGL(k_prep, dim3(9216), dim3(256), 0, stream, x, adj, W, St,
                       adjB);
    hipLaunchKernelGGL(k_gemm6, dim3(512), dim3(256), 0, stream, adjB, St, bias,
                       out, 4, 0);
  } else {
    // fallback half-split (not expected to run): one 2048-row panel reused
    unsigned short* adjH = St + (ST_B / 2);
    hipLaunchKernelGGL(k_support, dim3((B_SZ * N_SZ) / 256), dim3(256), 0,
                       stream, x, W, St);
    hipLaunchKernelGGL(k_cvt, dim3((2048 * 4096) / 2048), dim3(256), 0, stream,
                       adj, adjH);
    hipLaunchKernelGGL(k_gemm6, dim3(256), dim3(256), 0, stream, adjH, St, bias,
                       out, 2, 0);
    hipLaunchKernelGGL(k_cvt, dim3((2048 * 4096) / 2048), dim3(256), 0, stream,
                       adj + (size_t)2048 * 4096, adjH);
    hipLaunchKernelGGL(k_gemm6, dim3(256), dim3(256), 0, stream, adjH, St, bias,
                       out, 2, 2048);
  }
}